// Round 5
// baseline (347.725 us; speedup 1.0000x reference)
//
#include <hip/hip_runtime.h>
#include <hip/hip_cooperative_groups.h>
#include <math.h>

namespace cg = cooperative_groups;

#define BATCH    128
#define N_ATOMS  4096
#define NB       4095
#define NA       4094
#define NT       4093
#define FSTRIDE  184185                // floats per sample (= 9 * 20465)
#define ROWS     20465
#define CROWS    12288                 // coord elements (3*N_ATOMS)
#define BROWS    12285                 // bond elements  (3*NB)
#define AROWS    16376                 // angle elements (4*NA)
#define EPSV     1e-8f
#define THREADS  1024
#define WAVES    16
#define TPR      120                   // (v11 fallback)

// chunk split: chunk 23023 starts at float 92092 -> EXACT row split at 10232
// (rows 0..10231 all-cols in h0's chunks, rows 10232..20464 in h1's).
#define NCHUNK_FULL 46046
#define HCHUNK      23023              // chunks per half
#define SPLIT_ROW   10232

// ---- flat LDS layout (byte offsets), v15-verified ----
#define OFF_SCC  0                     // f32[12288]          49152 B
#define OFF_B    49152                 // u16[12288 res]      24576 B
#define OFF_A    73728                 // u16[16376]          32752 B
#define OFF_T    106480                // u16[20466 res]      40932 B
#define OFF_SBT  147412                // f32[30]
#define OFF_SAT  147532                // f32[26]
#define OFF_STT  147636                // f32[50]
#define OFF_SMU  147836                // f32[25]
#define OFF_SRED 147936                // f32[48]
#define OFF_D4   148128                // dummy f32 sink
#define OFF_D2   148132                // dummy u16 sink
#define LDS_SZ   148160

// ---- ws exchange layout (u32 units, per sample) ----
#define WC       0                     // coords f32[12288]   (h0: 0..10231, h1: tail)
#define WT       12288                 // tors u16[0..10231]   = 5116 u32 (h0 -> h1)
#define WB       17404                 // bonds u16[10232..12285) = 1027 u32 (+1 pad)
#define WA       18432                 // angles u16[10232..16375] = 3072 u32
#define WSLOT    21504                 // u32 per sample (86,016 B)
#define WS_NEED  ((size_t)WSLOT * 4 * BATCH)   // 11,010,048 B

typedef float float4a __attribute__((ext_vector_type(4), aligned(4)));

// v16: cooperative split-stream.
// Evidence (v11/v13/v15 triangulation): Phase A is PER-CU streaming-rate
// bound (~16-20 GB/s/CU; m13 chip copy = 24.6 GB/s/CU) -- mechanism
// (gather / staged / contiguous-extract) and total HBM traffic are
// second-order. So minimize MAX BYTES PER CU: 256 blocks, two per sample,
// each streams a disjoint half (368 KB) with v15's verified contiguous
// extractor; halves exchange the twin-needed compact columns through d_ws
// (11 MB each way) around one grid sync; Phase B is v11's twin split
// verbatim. Per-CU memory load: 368 + ~87 KB = ~455 KB vs v11's 737 KB.

__device__ __forceinline__ float sel4f(const float4a v, const int e) {
    float r = v.w;
    r = (e == 0) ? v.x : r;
    r = (e == 1) ? v.y : r;
    r = (e == 2) ? v.z : r;
    return r;                          // e outside [0,3] -> garbage (masked)
}

__device__ __forceinline__ void extract_chunk(char* __restrict__ lds,
                                              const float4a v,
                                              const int r0, const int c0) {
    {   // coord (col 5)
        const float cv = sel4f(v, 5 - c0);
        const bool  ok = ((unsigned)(5 - c0) < 4u) && (r0 < CROWS);
        const int   ad = ok ? (OFF_SCC + (r0 << 2)) : OFF_D4;
        *(float*)(lds + ad) = cv;
    }
    {   // bond (col 6)
        const int  iv = (int)sel4f(v, 6 - c0);
        const bool ok = ((unsigned)(6 - c0) < 4u) && (r0 < BROWS);
        const int  ad = ok ? (OFF_B + (r0 << 1)) : OFF_D2;
        *(unsigned short*)(lds + ad) = (unsigned short)iv;
    }
    {   // angle (col 7)
        const int  iv = (int)sel4f(v, 7 - c0);
        const bool ok = ((unsigned)(7 - c0) < 4u) && (r0 < AROWS);
        const int  ad = ok ? (OFF_A + (r0 << 1)) : OFF_D2;
        *(unsigned short*)(lds + ad) = (unsigned short)iv;
    }
    {   // torsion (col 8); full chunks never exceed row 20464 with e valid
        const int  iv = (int)sel4f(v, 8 - c0);
        const bool ok = ((unsigned)(8 - c0) < 4u);
        const int  ad = ok ? (OFF_T + (r0 << 1)) : OFF_D2;
        *(unsigned short*)(lds + ad) = (unsigned short)iv;
    }
}

__global__ __launch_bounds__(THREADS, 1) void
local_energy_v16(const float* __restrict__ F,
                 const float* __restrict__ bond_type,
                 const float* __restrict__ angle_type,
                 const float* __restrict__ tor_type,
                 const int*   __restrict__ multiplicity,
                 const float* __restrict__ opt_pars,
                 unsigned*    __restrict__ ws,
                 float*       __restrict__ out)
{
    __shared__ __align__(16) char LDSM[LDS_SZ];
    char* lds = LDSM;

    const int b   = blockIdx.x;
    const int s   = b >> 1;            // sample 0..127
    const int h   = b & 1;             // 0: rows<10232 owner; 1: rows>=10232
    const int tid = threadIdx.x;
    const int w   = tid >> 6;
    const int l   = tid & 63;
    const float* Fb = F + (size_t)s * FSTRIDE;

    float* sbt = (float*)(lds + OFF_SBT);
    float* sat = (float*)(lds + OFF_SAT);
    float* stt = (float*)(lds + OFF_STT);
    float* smu = (float*)(lds + OFF_SMU);
    float* srd = (float*)(lds + OFF_SRED);

    if (tid < 30)                      sbt[tid]       = bond_type[tid];
    else if (tid >= 32 && tid < 58)    sat[tid - 32]  = angle_type[tid - 32];
    else if (tid >= 64 && tid < 114)   stt[tid - 64]  = tor_type[tid - 64];
    else if (tid >= 128 && tid < 153)  smu[tid - 128] = (float)multiplicity[tid - 128];

    // ======== Phase A: disjoint half-stream + scatter extract (v15 core) ====
    const int cbase = h ? HCHUNK : 0;  // 23023 chunks per half (= 368 KB)
    {
        const int f0i = 4 * (cbase + tid);
        int r0 = f0i / 9;              // magic-mul div, once
        int c0 = f0i - 9 * r0;

        for (int j = 0; j < 22; j += 2) {      // pairs: 2 loads in flight
            const int ci0 = cbase + tid + (j << 10);
            const float4a v0 = *(const float4a*)(Fb + 4 * ci0);
            const float4a v1 = *(const float4a*)(Fb + 4 * ci0 + 4096);
            extract_chunk(lds, v0, r0, c0);
            { c0 += 1; r0 += 455; if (c0 == 9) { c0 = 0; r0 += 1; } }
            extract_chunk(lds, v1, r0, c0);
            { c0 += 1; r0 += 455; if (c0 == 9) { c0 = 0; r0 += 1; } }
        }
        // j = 22 partial: 495 chunks; h1 tail float (184184 = row 20464 col 8)
        if (tid < 495) {
            const int ci = cbase + tid + (22 << 10);
            const float4a v = *(const float4a*)(Fb + 4 * ci);
            extract_chunk(lds, v, r0, c0);
        } else if (h && tid == 495) {
            const float x = Fb[FSTRIDE - 1];
            *(unsigned short*)(lds + OFF_T + (20464 << 1)) = (unsigned short)(int)x;
        }
    }
    __syncthreads();

    // ======== Exchange OUT: own compact halves -> ws (coalesced u32) ========
    unsigned* W = ws + (size_t)s * WSLOT;
    if (h == 0) {
        const unsigned* sC = (const unsigned*)(lds + OFF_SCC);
        for (int i = tid; i < 10232; i += THREADS) W[WC + i] = sC[i];
        const unsigned* sT = (const unsigned*)(lds + OFF_T);
        for (int i = tid; i < 5116; i += THREADS) W[WT + i] = sT[i];
    } else {
        const unsigned* sC = (const unsigned*)(lds + OFF_SCC);
        for (int i = tid; i < 2056; i += THREADS) W[WC + SPLIT_ROW + i] = sC[SPLIT_ROW + i];
        const unsigned* sB = (const unsigned*)(lds + OFF_B);
        for (int i = tid; i < 1027; i += THREADS) W[WB + i] = sB[5116 + i];
        const unsigned* sA = (const unsigned*)(lds + OFF_A);
        for (int i = tid; i < 3072; i += THREADS) W[WA + i] = sA[5116 + i];
    }

    // Device-scope release (cross-XCD L2 writeback), grid barrier, acquire.
    __threadfence();
    cg::this_grid().sync();
    __threadfence();

    // ======== Exchange IN: twin's halves -> LDS ========
    if (h == 0) {
        unsigned* dC = (unsigned*)(lds + OFF_SCC);
        for (int i = tid; i < 2056; i += THREADS) dC[SPLIT_ROW + i] = W[WC + SPLIT_ROW + i];
        unsigned* dB = (unsigned*)(lds + OFF_B);
        for (int i = tid; i < 1027; i += THREADS) dB[5116 + i] = W[WB + i];
        unsigned* dA = (unsigned*)(lds + OFF_A);
        for (int i = tid; i < 3072; i += THREADS) dA[5116 + i] = W[WA + i];
    } else {
        unsigned* dC = (unsigned*)(lds + OFF_SCC);
        for (int i = tid; i < 10232; i += THREADS) dC[i] = W[WC + i];
        unsigned* dT = (unsigned*)(lds + OFF_T);
        for (int i = tid; i < 5116; i += THREADS) dT[i] = W[WT + i];
    }
    __syncthreads();

    const float*          scc = (const float*)(lds + OFF_SCC);
    const unsigned short* pB  = (const unsigned short*)(lds + OFF_B);
    const unsigned short* pA  = (const unsigned short*)(lds + OFF_A);
    const unsigned short* pT  = (const unsigned short*)(lds + OFF_T);

    // ======== Phase B: v11 twin split, verbatim (identical numerics) ========
    float eA = 0.f, eB = 0.f;          // h0: eA=bond eB=angle | h1: eA=tor
    if (h == 0) {
        for (int i = tid; i < NB; i += THREADS) {
            const int a0 = pB[3 * i + 0];
            const int a1 = pB[3 * i + 1];
            const int bt = pB[3 * i + 2];
            const float dx = scc[3 * a0 + 0] - scc[3 * a1 + 0];
            const float dy = scc[3 * a0 + 1] - scc[3 * a1 + 1];
            const float dz = scc[3 * a0 + 2] - scc[3 * a1 + 2];
            const float r  = sqrtf(dx * dx + dy * dy + dz * dz + EPSV);
            const float t0 = r - sbt[bt * 2 + 1];
            eA += sbt[bt * 2 + 0] * t0 * t0;
        }
        for (int i = tid; i < NA; i += THREADS) {
            const int a0 = pA[4 * i + 0];
            const int a1 = pA[4 * i + 1];
            const int a2 = pA[4 * i + 2];
            const int at = pA[4 * i + 3];
            const float v1x = scc[3 * a0 + 0] - scc[3 * a1 + 0];
            const float v1y = scc[3 * a0 + 1] - scc[3 * a1 + 1];
            const float v1z = scc[3 * a0 + 2] - scc[3 * a1 + 2];
            const float v2x = scc[3 * a2 + 0] - scc[3 * a1 + 0];
            const float v2y = scc[3 * a2 + 1] - scc[3 * a1 + 1];
            const float v2z = scc[3 * a2 + 2] - scc[3 * a1 + 2];
            const float d12 = v1x * v2x + v1y * v2y + v1z * v2z;
            const float n1  = sqrtf(v1x * v1x + v1y * v1y + v1z * v1z + EPSV);
            const float n2  = sqrtf(v2x * v2x + v2y * v2y + v2z * v2z + EPSV);
            float cosang = d12 / (n1 * n2);
            cosang = fminf(fmaxf(cosang, -1.0f + 1e-6f), 1.0f - 1e-6f);
            const float t0 = acosf(cosang) - sat[at * 2 + 1];
            eB += sat[at * 2 + 0] * t0 * t0;
        }
    } else {
        for (int i = tid; i < NT; i += THREADS) {
            const int ai = pT[5 * i + 0];
            const int aj = pT[5 * i + 1];
            const int ak = pT[5 * i + 2];
            const int al = pT[5 * i + 3];
            const int tt = pT[5 * i + 4];
            const float b1x = scc[3*aj+0] - scc[3*ai+0];
            const float b1y = scc[3*aj+1] - scc[3*ai+1];
            const float b1z = scc[3*aj+2] - scc[3*ai+2];
            const float b2x = scc[3*ak+0] - scc[3*aj+0];
            const float b2y = scc[3*ak+1] - scc[3*aj+1];
            const float b2z = scc[3*ak+2] - scc[3*aj+2];
            const float b3x = scc[3*al+0] - scc[3*ak+0];
            const float b3y = scc[3*al+1] - scc[3*ak+1];
            const float b3z = scc[3*al+2] - scc[3*ak+2];
            const float n1x = b1y*b2z - b1z*b2y;
            const float n1y = b1z*b2x - b1x*b2z;
            const float n1z = b1x*b2y - b1y*b2x;
            const float n2x = b2y*b3z - b2z*b3y;
            const float n2y = b2z*b3x - b2x*b3z;
            const float n2z = b2x*b3y - b2y*b3x;
            const float inv = 1.0f / sqrtf(b2x*b2x + b2y*b2y + b2z*b2z + EPSV);
            const float bnx = b2x * inv, bny = b2y * inv, bnz = b2z * inv;
            const float m1x = n1y*bnz - n1z*bny;
            const float m1y = n1z*bnx - n1x*bnz;
            const float m1z = n1x*bny - n1y*bnx;
            const float phi = atan2f(m1x*n2x + m1y*n2y + m1z*n2z,
                                     n1x*n2x + n1y*n2y + n1z*n2z);
            eA += stt[tt * 2 + 0] * (1.0f + cosf(smu[tt] * phi - stt[tt * 2 + 1]));
        }
    }

    for (int off = 32; off > 0; off >>= 1) {
        eA += __shfl_down(eA, off);
        eB += __shfl_down(eB, off);
    }
    if (l == 0) {
        srd[w * 2 + 0] = eA;
        srd[w * 2 + 1] = eB;
    }
    __syncthreads();
    if (tid == 0) {
        float rA = 0.f, rB = 0.f;
        for (int i = 0; i < WAVES; ++i) { rA += srd[i * 2]; rB += srd[i * 2 + 1]; }
        if (h == 0) {
            out[s * 3 + 0] = opt_pars[0] * rA;   // bonds
            out[s * 3 + 1] = opt_pars[1] * rB;   // angles
        } else {
            out[s * 3 + 2] = opt_pars[2] * rA;   // torsions
        }
    }
}

// ======================= Fallback: v11 (best known-good) =======================
typedef float float4f __attribute__((ext_vector_type(4), aligned(4)));

__global__ __launch_bounds__(THREADS, 1) void
local_energy_v11(const float* __restrict__ F,
                 const float* __restrict__ bond_type,
                 const float* __restrict__ angle_type,
                 const float* __restrict__ tor_type,
                 const int*   __restrict__ multiplicity,
                 const float* __restrict__ opt_pars,
                 float*       __restrict__ out)
{
    __shared__ float          scc[CROWS];
    __shared__ unsigned short sbB[BROWS + 1];
    __shared__ unsigned short sbA[AROWS];
    __shared__ unsigned short sbT[ROWS + 1];
    __shared__ float sbt[30], sat[26], stt[50], smu[25];
    __shared__ float sred[WAVES * 2];

    const int b   = blockIdx.x;
    const int x   = b & 7;
    const int g   = b >> 3;
    const int s   = (g & 15) * 8 + x;
    const int p   = g >> 4;
    const int tid = threadIdx.x;
    const int w   = tid >> 6;
    const int l   = tid & 63;
    const size_t sbase = (size_t)s * FSTRIDE;

    if (tid < 30)                      sbt[tid]       = bond_type[tid];
    else if (tid >= 32 && tid < 58)    sat[tid - 32]  = angle_type[tid - 32];
    else if (tid >= 64 && tid < 114)   stt[tid - 64]  = tor_type[tid - 64];
    else if (tid >= 128 && tid < 153)  smu[tid - 128] = (float)multiplicity[tid - 128];

    const int tmax = p ? 137 : 171;
    for (int t = w; t < tmax; t += WAVES) {
        const int R0 = TPR * t + 2 * l;
        const int R1 = R0 + 1;
        float4f v0, v1;
        const bool ok0 = (R0 < ROWS);
        const bool ok1 = (R1 < ROWS);
        if (ok0) v0 = *(const float4f*)(F + sbase + (size_t)9 * R0 + 5);
        if (ok1) v1 = *(const float4f*)(F + sbase + (size_t)9 * R1 + 5);
        if (R1 < CROWS) {
            float2 c2; c2.x = v0.x; c2.y = v1.x;
            *(float2*)(scc + R0) = c2;
        }
        if (p) {
            if (R1 < BROWS) {
                unsigned pk = (unsigned)(unsigned short)(int)v0.y
                            | ((unsigned)(unsigned short)(int)v1.y << 16);
                *(unsigned*)(sbB + R0) = pk;
            } else if (R0 < BROWS) {
                sbB[R0] = (unsigned short)(int)v0.y;
            }
            if (R1 < AROWS) {
                unsigned pk = (unsigned)(unsigned short)(int)v0.z
                            | ((unsigned)(unsigned short)(int)v1.z << 16);
                *(unsigned*)(sbA + R0) = pk;
            }
        } else {
            if (ok1) {
                unsigned pk = (unsigned)(unsigned short)(int)v0.w
                            | ((unsigned)(unsigned short)(int)v1.w << 16);
                *(unsigned*)(sbT + R0) = pk;
            } else if (ok0) {
                sbT[R0] = (unsigned short)(int)v0.w;
            }
        }
    }
    __syncthreads();

    float eA = 0.f, eB = 0.f;
    if (p) {
        for (int i = tid; i < NB; i += THREADS) {
            const int a0 = sbB[3 * i + 0];
            const int a1 = sbB[3 * i + 1];
            const int bt = sbB[3 * i + 2];
            const float dx = scc[3 * a0 + 0] - scc[3 * a1 + 0];
            const float dy = scc[3 * a0 + 1] - scc[3 * a1 + 1];
            const float dz = scc[3 * a0 + 2] - scc[3 * a1 + 2];
            const float r  = sqrtf(dx * dx + dy * dy + dz * dz + EPSV);
            const float t0 = r - sbt[bt * 2 + 1];
            eA += sbt[bt * 2 + 0] * t0 * t0;
        }
        for (int i = tid; i < NA; i += THREADS) {
            const int a0 = sbA[4 * i + 0];
            const int a1 = sbA[4 * i + 1];
            const int a2 = sbA[4 * i + 2];
            const int at = sbA[4 * i + 3];
            const float v1x = scc[3 * a0 + 0] - scc[3 * a1 + 0];
            const float v1y = scc[3 * a0 + 1] - scc[3 * a1 + 1];
            const float v1z = scc[3 * a0 + 2] - scc[3 * a1 + 2];
            const float v2x = scc[3 * a2 + 0] - scc[3 * a1 + 0];
            const float v2y = scc[3 * a2 + 1] - scc[3 * a1 + 1];
            const float v2z = scc[3 * a2 + 2] - scc[3 * a1 + 2];
            const float d12 = v1x * v2x + v1y * v2y + v1z * v2z;
            const float n1  = sqrtf(v1x * v1x + v1y * v1y + v1z * v1z + EPSV);
            const float n2  = sqrtf(v2x * v2x + v2y * v2y + v2z * v2z + EPSV);
            float cosang = d12 / (n1 * n2);
            cosang = fminf(fmaxf(cosang, -1.0f + 1e-6f), 1.0f - 1e-6f);
            const float t0 = acosf(cosang) - sat[at * 2 + 1];
            eB += sat[at * 2 + 0] * t0 * t0;
        }
    } else {
        for (int i = tid; i < NT; i += THREADS) {
            const int ai = sbT[5 * i + 0];
            const int aj = sbT[5 * i + 1];
            const int ak = sbT[5 * i + 2];
            const int al = sbT[5 * i + 3];
            const int tt = sbT[5 * i + 4];
            const float b1x = scc[3*aj+0] - scc[3*ai+0];
            const float b1y = scc[3*aj+1] - scc[3*ai+1];
            const float b1z = scc[3*aj+2] - scc[3*ai+2];
            const float b2x = scc[3*ak+0] - scc[3*aj+0];
            const float b2y = scc[3*ak+1] - scc[3*aj+1];
            const float b2z = scc[3*ak+2] - scc[3*aj+2];
            const float b3x = scc[3*al+0] - scc[3*ak+0];
            const float b3y = scc[3*al+1] - scc[3*ak+1];
            const float b3z = scc[3*al+2] - scc[3*ak+2];
            const float n1x = b1y*b2z - b1z*b2y;
            const float n1y = b1z*b2x - b1x*b2z;
            const float n1z = b1x*b2y - b1y*b2x;
            const float n2x = b2y*b3z - b2z*b3y;
            const float n2y = b2z*b3x - b2x*b3z;
            const float n2z = b2x*b3y - b2y*b3x;
            const float inv = 1.0f / sqrtf(b2x*b2x + b2y*b2y + b2z*b2z + EPSV);
            const float bnx = b2x * inv, bny = b2y * inv, bnz = b2z * inv;
            const float m1x = n1y*bnz - n1z*bny;
            const float m1y = n1z*bnx - n1x*bnz;
            const float m1z = n1x*bny - n1y*bnx;
            const float phi = atan2f(m1x*n2x + m1y*n2y + m1z*n2z,
                                     n1x*n2x + n1y*n2y + n1z*n2z);
            eA += stt[tt * 2 + 0] * (1.0f + cosf(smu[tt] * phi - stt[tt * 2 + 1]));
        }
    }

    for (int off = 32; off > 0; off >>= 1) {
        eA += __shfl_down(eA, off);
        eB += __shfl_down(eB, off);
    }
    if (l == 0) {
        sred[w * 2 + 0] = eA;
        sred[w * 2 + 1] = eB;
    }
    __syncthreads();
    if (tid == 0) {
        float rA = 0.f, rB = 0.f;
        for (int i = 0; i < WAVES; ++i) { rA += sred[i * 2]; rB += sred[i * 2 + 1]; }
        if (p) {
            out[s * 3 + 0] = opt_pars[0] * rA;
            out[s * 3 + 1] = opt_pars[1] * rB;
        } else {
            out[s * 3 + 2] = opt_pars[2] * rA;
        }
    }
}

extern "C" void kernel_launch(void* const* d_in, const int* in_sizes, int n_in,
                              void* d_out, int out_size, void* d_ws, size_t ws_size,
                              hipStream_t stream) {
    const float* F            = (const float*)d_in[0];
    // d_in[1] = lengths (constant, unused)
    const float* bond_type    = (const float*)d_in[2];
    const float* angle_type   = (const float*)d_in[3];
    const float* tor_type     = (const float*)d_in[4];
    const int*   multiplicity = (const int*)  d_in[5];
    const float* opt_pars     = (const float*)d_in[6];
    float*       out          = (float*)d_out;
    unsigned*    wsp          = (unsigned*)d_ws;

    if (d_ws != nullptr && ws_size >= WS_NEED) {
        void* args[] = { (void*)&F, (void*)&bond_type, (void*)&angle_type,
                         (void*)&tor_type, (void*)&multiplicity,
                         (void*)&opt_pars, (void*)&wsp, (void*)&out };
        hipError_t e = hipLaunchCooperativeKernel(
            reinterpret_cast<void*>(local_energy_v16),
            dim3(BATCH * 2), dim3(THREADS), args, 0, stream);
        if (e == hipSuccess) return;
        (void)hipGetLastError();       // clear error, fall through
    }
    // Fallback: best known-good single kernel (v11).
    local_energy_v11<<<dim3(BATCH * 2), dim3(THREADS), 0, stream>>>(
        F, bond_type, angle_type, tor_type, multiplicity, opt_pars, out);
}

// Round 6
// 156.092 us; speedup vs baseline: 2.2277x; 2.2277x over previous
//
#include <hip/hip_runtime.h>
#include <math.h>

#define BATCH    128
#define N_ATOMS  4096
#define NB       4095
#define NA       4094
#define NT       4093
#define FSTRIDE  184185                // floats per sample
#define ROWS     20465                 // MAX_LEN rows of 9 floats
#define CROWS    12288                 // coord elements (3*N_ATOMS)
#define BROWS    12285                 // bond elements  (3*NB)
#define AROWS    16376                 // angle elements (4*NA)
#define EPSV     1e-8f
#define THREADS  1024
#define WAVES    16
#define TPR      120                   // rows per tile (2 rows per lane)
#define HEAD_T   103                   // head tiles 0..102 -> rows 0..12359
#define CUT_T    2472                  // torsion entries w/ all rows <= 12359

// 4-byte-aligned float4: cols 5..8 of row R are contiguous at float 9R+5.
typedef float float4a __attribute__((ext_vector_type(4), aligned(4)));

// v17 = v11 + stream/compute tail overlap.
// Ledger: v12 (-fetch dup, 1 blk/sample) +12us; v13 (staged contiguous) +10;
// v14 (two-pass ws) +14; v16 (coop sync) +169 (cg::sync+fences ~175us idle,
// measured directly). v11's twin-gather structure is the floor of every
// restructuring: ~30us stream (at both chip- and per-CU-BW limits, L3
// absorbing part of the twin duplication) + ~7us SERIAL Phase-B tail.
// v17 removes the only free slack: after head tiles 0..102 (rows<12360:
// all coords, all bonds, torsion rows of entries <2472), the tail gather
// is interleaved with the already-computable Phase-B chunks, hiding ~4us
// (p0) / ~2.5us (p1) of VALU under the tail stream. Per-thread partial-sum
// order is IDENTICAL to v11 (same i = tid+1024k ascending sequence).

__device__ __forceinline__ float bond_term(const int i,
        const unsigned short* __restrict__ sbB,
        const float* __restrict__ scc,
        const float* __restrict__ sbt)
{
    const int a0 = sbB[3 * i + 0];
    const int a1 = sbB[3 * i + 1];
    const int bt = sbB[3 * i + 2];
    const float dx = scc[3 * a0 + 0] - scc[3 * a1 + 0];
    const float dy = scc[3 * a0 + 1] - scc[3 * a1 + 1];
    const float dz = scc[3 * a0 + 2] - scc[3 * a1 + 2];
    const float r  = sqrtf(dx * dx + dy * dy + dz * dz + EPSV);
    const float t0 = r - sbt[bt * 2 + 1];
    return sbt[bt * 2 + 0] * t0 * t0;
}

__device__ __forceinline__ float tor_term(const int i,
        const unsigned short* __restrict__ sbT,
        const float* __restrict__ scc,
        const float* __restrict__ stt,
        const float* __restrict__ smu)
{
    const int ai = sbT[5 * i + 0];
    const int aj = sbT[5 * i + 1];
    const int ak = sbT[5 * i + 2];
    const int al = sbT[5 * i + 3];
    const int tt = sbT[5 * i + 4];
    const float b1x = scc[3*aj+0] - scc[3*ai+0];
    const float b1y = scc[3*aj+1] - scc[3*ai+1];
    const float b1z = scc[3*aj+2] - scc[3*ai+2];
    const float b2x = scc[3*ak+0] - scc[3*aj+0];
    const float b2y = scc[3*ak+1] - scc[3*aj+1];
    const float b2z = scc[3*ak+2] - scc[3*aj+2];
    const float b3x = scc[3*al+0] - scc[3*ak+0];
    const float b3y = scc[3*al+1] - scc[3*ak+1];
    const float b3z = scc[3*al+2] - scc[3*ak+2];
    const float n1x = b1y*b2z - b1z*b2y;
    const float n1y = b1z*b2x - b1x*b2z;
    const float n1z = b1x*b2y - b1y*b2x;
    const float n2x = b2y*b3z - b2z*b3y;
    const float n2y = b2z*b3x - b2x*b3z;
    const float n2z = b2x*b3y - b2y*b3x;
    const float inv = 1.0f / sqrtf(b2x*b2x + b2y*b2y + b2z*b2z + EPSV);
    const float bnx = b2x * inv, bny = b2y * inv, bnz = b2z * inv;
    const float m1x = n1y*bnz - n1z*bny;
    const float m1y = n1z*bnx - n1x*bnz;
    const float m1z = n1x*bny - n1y*bnx;
    const float phi = atan2f(m1x*n2x + m1y*n2y + m1z*n2z,
                             n1x*n2x + n1y*n2y + n1z*n2z);
    return stt[tt * 2 + 0] * (1.0f + cosf(smu[tt] * phi - stt[tt * 2 + 1]));
}

__global__ __launch_bounds__(THREADS, 1) void
local_energy_v17(const float* __restrict__ F,
                 const float* __restrict__ bond_type,   // 15 x 2
                 const float* __restrict__ angle_type,  // 13 x 2
                 const float* __restrict__ tor_type,    // 25 x 2
                 const int*   __restrict__ multiplicity,// 25
                 const float* __restrict__ opt_pars,    // 47
                 float*       __restrict__ out)         // B x 3
{
    __shared__ float          scc[CROWS];   // coords: atom a = scc[3a+c]
    __shared__ unsigned short sbB[BROWS + 1];
    __shared__ unsigned short sbA[AROWS];
    __shared__ unsigned short sbT[ROWS + 1];
    __shared__ float sbt[30], sat[26], stt[50], smu[25];
    __shared__ float sred[WAVES * 2];

    const int b   = blockIdx.x;
    const int x   = b & 7;             // XCD slot (twins share it)
    const int g   = b >> 3;            // 0..31
    const int s   = (g & 15) * 8 + x;  // sample 0..127
    const int p   = g >> 4;            // 0: torsions   1: bonds + angles
    const int tid = threadIdx.x;
    const int w   = tid >> 6;
    const int l   = tid & 63;
    const size_t sbase = (size_t)s * FSTRIDE;

    if (tid < 30)                      sbt[tid]       = bond_type[tid];
    else if (tid >= 32 && tid < 58)    sat[tid - 32]  = angle_type[tid - 32];
    else if (tid >= 64 && tid < 114)   stt[tid - 64]  = tor_type[tid - 64];
    else if (tid >= 128 && tid < 153)  smu[tid - 128] = (float)multiplicity[tid - 128];

    float eA = 0.f, eB = 0.f;          // p0: eA=tor | p1: eA=bond, eB=angle

    // ======== Phase A-head: tiles 0..102 (rows 0..12359) ========
    // Identical to v11's loop body restricted to t < HEAD_T. All rows here
    // are < 12368 < AROWS/ROWS, so only coord/bond guards matter.
    for (int t = w; t < HEAD_T; t += WAVES) {
        const int R0 = TPR * t + 2 * l;          // even
        const int R1 = R0 + 1;
        const float4a v0 = *(const float4a*)(F + sbase + (size_t)9 * R0 + 5);
        const float4a v1 = *(const float4a*)(F + sbase + (size_t)9 * R1 + 5);

        if (R1 < CROWS) {                        // coords (even count)
            float2 c2; c2.x = v0.x; c2.y = v1.x;
            *(float2*)(scc + R0) = c2;
        }
        if (p) {
            if (R1 < BROWS) {                    // bonds (odd -> tail single)
                unsigned pk = (unsigned)(unsigned short)(int)v0.y
                            | ((unsigned)(unsigned short)(int)v1.y << 16);
                *(unsigned*)(sbB + R0) = pk;
            } else if (R0 < BROWS) {
                sbB[R0] = (unsigned short)(int)v0.y;
            }
            {                                    // angles (always in range here)
                unsigned pk = (unsigned)(unsigned short)(int)v0.z
                            | ((unsigned)(unsigned short)(int)v1.z << 16);
                *(unsigned*)(sbA + R0) = pk;
            }
        } else {
            {                                    // torsions (always in range here)
                unsigned pk = (unsigned)(unsigned short)(int)v0.w
                            | ((unsigned)(unsigned short)(int)v1.w << 16);
                *(unsigned*)(sbT + R0) = pk;
            }
        }
    }
    __syncthreads();
    // Now complete in LDS: coords [0,12288), bonds [0,12285), angles rows
    // [0,12360), torsion rows [0,12360) -> entries < CUT_T computable.

    // ======== Phase A-tail + overlapped compute ========
    if (p) {
        // tail tiles 103..136 (rows 12360..16439): angles only.
        // All bond entries computable -> 2 chunks per tail iteration.
        int q = 0;
        for (int t = HEAD_T + w; t < 137; t += WAVES) {
            const int R0 = TPR * t + 2 * l;
            const int R1 = R0 + 1;
            const float4a v0 = *(const float4a*)(F + sbase + (size_t)9 * R0 + 5);
            const float4a v1 = *(const float4a*)(F + sbase + (size_t)9 * R1 + 5);

            if (q == 0) {                        // i = tid, tid+1024
                eA += bond_term(tid, sbB, scc, sbt);
                eA += bond_term(tid + 1024, sbB, scc, sbt);
            } else if (q == 1) {                 // i = tid+2048, tid+3072
                eA += bond_term(tid + 2048, sbB, scc, sbt);
                if (tid + 3072 < NB) eA += bond_term(tid + 3072, sbB, scc, sbt);
            }
            ++q;

            if (R1 < AROWS) {
                unsigned pk = (unsigned)(unsigned short)(int)v0.z
                            | ((unsigned)(unsigned short)(int)v1.z << 16);
                *(unsigned*)(sbA + R0) = pk;
            }
        }
        // Waves with <2 tail iterations don't exist (min 2 for w=2..15);
        // w=0,1 get a 3rd iteration with q=2 -> no compute, extract only.
        __syncthreads();

        // angles: full loop (striding identical to v11)
        for (int i = tid; i < NA; i += THREADS) {
            const int a0 = sbA[4 * i + 0];
            const int a1 = sbA[4 * i + 1];
            const int a2 = sbA[4 * i + 2];
            const int at = sbA[4 * i + 3];
            const float v1x = scc[3 * a0 + 0] - scc[3 * a1 + 0];
            const float v1y = scc[3 * a0 + 1] - scc[3 * a1 + 1];
            const float v1z = scc[3 * a0 + 2] - scc[3 * a1 + 2];
            const float v2x = scc[3 * a2 + 0] - scc[3 * a1 + 0];
            const float v2y = scc[3 * a2 + 1] - scc[3 * a1 + 1];
            const float v2z = scc[3 * a2 + 2] - scc[3 * a1 + 2];
            const float d12 = v1x * v2x + v1y * v2y + v1z * v2z;
            const float n1  = sqrtf(v1x * v1x + v1y * v1y + v1z * v1z + EPSV);
            const float n2  = sqrtf(v2x * v2x + v2y * v2y + v2z * v2z + EPSV);
            float cosang = d12 / (n1 * n2);
            cosang = fminf(fmaxf(cosang, -1.0f + 1e-6f), 1.0f - 1e-6f);
            const float t0 = acosf(cosang) - sat[at * 2 + 1];
            eB += sat[at * 2 + 0] * t0 * t0;
        }
    } else {
        // tail tiles 103..170 (rows 12360..20464): torsions only.
        // Torsion entries < CUT_T computable -> 1 chunk per tail iteration.
        int q = 0;
        for (int t = HEAD_T + w; t < 171; t += WAVES) {
            const int R0 = TPR * t + 2 * l;
            const int R1 = R0 + 1;
            float4a v0, v1;
            const bool ok0 = (R0 < ROWS);
            const bool ok1 = (R1 < ROWS);
            if (ok0) v0 = *(const float4a*)(F + sbase + (size_t)9 * R0 + 5);
            if (ok1) v1 = *(const float4a*)(F + sbase + (size_t)9 * R1 + 5);

            if (q < 3) {                         // i = tid + 1024q  (< CUT_T)
                const int i = tid + (q << 10);
                if (i < CUT_T) eA += tor_term(i, sbT, scc, stt, smu);
            }
            ++q;

            if (ok1) {
                unsigned pk = (unsigned)(unsigned short)(int)v0.w
                            | ((unsigned)(unsigned short)(int)v1.w << 16);
                *(unsigned*)(sbT + R0) = pk;
            } else if (ok0) {
                sbT[R0] = (unsigned short)(int)v0.w;
            }
        }
        // All waves have >= 4 tail iterations -> chunks 0..2 all placed.
        __syncthreads();

        // remaining torsion entries (i >= CUT_T); per-thread order stays
        // ascending -> bit-identical partial sums vs v11.
        for (int i = tid; i < NT; i += THREADS)
            if (i >= CUT_T) eA += tor_term(i, sbT, scc, stt, smu);
    }

    // ======== Reduction + disjoint plain stores ========
    for (int off = 32; off > 0; off >>= 1) {
        eA += __shfl_down(eA, off);
        eB += __shfl_down(eB, off);
    }
    if (l == 0) {
        sred[w * 2 + 0] = eA;
        sred[w * 2 + 1] = eB;
    }
    __syncthreads();
    if (tid == 0) {
        float rA = 0.f, rB = 0.f;
        for (int i = 0; i < WAVES; ++i) { rA += sred[i * 2]; rB += sred[i * 2 + 1]; }
        if (p) {
            out[s * 3 + 0] = opt_pars[0] * rA;   // bonds
            out[s * 3 + 1] = opt_pars[1] * rB;   // angles
        } else {
            out[s * 3 + 2] = opt_pars[2] * rA;   // torsions
        }
    }
}

extern "C" void kernel_launch(void* const* d_in, const int* in_sizes, int n_in,
                              void* d_out, int out_size, void* d_ws, size_t ws_size,
                              hipStream_t stream) {
    const float* F            = (const float*)d_in[0];
    // d_in[1] = lengths (constant, unused)
    const float* bond_type    = (const float*)d_in[2];
    const float* angle_type   = (const float*)d_in[3];
    const float* tor_type     = (const float*)d_in[4];
    const int*   multiplicity = (const int*)  d_in[5];
    const float* opt_pars     = (const float*)d_in[6];
    float* out = (float*)d_out;

    // Twin blocks per sample; every out element written exactly once by
    // plain stores -> no memset / atomics / workspace / cooperative launch.
    local_energy_v17<<<dim3(BATCH * 2), dim3(THREADS), 0, stream>>>(
        F, bond_type, angle_type, tor_type, multiplicity, opt_pars, out);
}